// Round 3
// baseline (7046.805 us; speedup 1.0000x reference)
//
#include <hip/hip_runtime.h>
#include <cstdint>
#include <cmath>

typedef unsigned short u16;
typedef unsigned int u32;
typedef __attribute__((ext_vector_type(8))) short bf16x8;
typedef __attribute__((ext_vector_type(4))) float f32x4;

// ---- model dims ----
#define B_    8
#define T_IN  2048
#define CIN1  273
#define L1_   1025
#define L_    513
#define C_    512
#define CE_   576
#define M1_   (B_*L1_)   /* 8200 */
#define M_    (B_*L_)    /* 4104 */
#define K1_   (CIN1*4)   /* 1092 */
#define H_    8
#define D_    64
#define R_    50

__device__ __forceinline__ u32 f2bf_rne(float f) {
    u32 x = __float_as_uint(f);
    return (x + 0x7fffu + ((x >> 16) & 1u)) >> 16;
}

// ======================= A-pair loader: returns packed bf16x2 for (k, k+1), k even ==============
// amode: 2 conv1 im2col from meg (fp32); 5 conv2 im2col from x1b (bf16, k-order kk*512+ci);
//        6 bf16 rowmajor(lda)
__device__ __forceinline__ u32 a_pair(const void* A, int m, int k, int lda, int amode, int Ksz) {
    if (amode == 2) {
        if (k >= K1_) return 0;
        int b = m / L1_, t = m - b * L1_;
        int ci = k >> 2, kk = k & 3;
        int it = 2 * t - 2 + kk;
        const float* mg = (const float*)A + ((size_t)(b * CIN1 + ci)) * T_IN;
        u32 lo = ((unsigned)it < (unsigned)T_IN)       ? f2bf_rne(mg[it])     : 0;
        u32 hi = ((unsigned)(it + 1) < (unsigned)T_IN) ? f2bf_rne(mg[it + 1]) : 0;
        return lo | (hi << 16);
    } else if (amode == 5) {
        int b = m / L_, t = m - b * L_;
        int kk = k >> 9, ci = k & 511;
        int it = 2 * t - 2 + kk;
        if ((unsigned)it >= (unsigned)L1_) return 0;
        return *(const u32*)((const u16*)A + ((size_t)(b * L1_ + it)) * 512 + ci);
    } else {
        return *(const u32*)((const u16*)A + (size_t)m * lda + k);
    }
}

// ======================= MFMA GEMM 64x64 (packed bf16 B) =======================
// cmode: 0 fp32 C[m*ldc+n]; 1 out[b][n][t] (n<128); 2 fp32 [(t*8+b)*ldc+n]; 3 bf16 Cb[m*ldc+n]
__global__ __launch_bounds__(256) void gemm_kernel(
    const void* __restrict__ Aptr, const u32* __restrict__ Bp,
    const float* __restrict__ bias1, const float* __restrict__ bias2,
    float* __restrict__ Cf, u16* __restrict__ Cb,
    int Msz, int Nsz, int Ksz, int lda, int ldc, int amode, int cmode, int relu)
{
    __shared__ u16 As[64][40];
    __shared__ u16 Bs[64][40];

    int tid = threadIdx.x;
    int m0 = blockIdx.x * 64, n0 = blockIdx.y * 64;
    int wv = tid >> 6, lane = tid & 63;
    int lm = lane & 15, quad = lane >> 4;
    int kp = tid & 15, rw = tid >> 4;
    int Kh = Ksz >> 1;

    f32x4 acc[4];
#pragma unroll
    for (int nt = 0; nt < 4; ++nt)
#pragma unroll
        for (int r = 0; r < 4; ++r) acc[nt][r] = 0.f;

    for (int k0 = 0; k0 < Ksz; k0 += 32) {
        int pidx = (k0 >> 1) + kp;
#pragma unroll
        for (int i = 0; i < 4; ++i) {
            int row = rw + 16 * i;
            int k = k0 + 2 * kp;
            int m = m0 + row;
            u32 aw = 0;
            if (m < Msz && k < Ksz) aw = a_pair(Aptr, m, k, lda, amode, Ksz);
            *(u32*)&As[row][2 * kp] = aw;
            u32 bw = 0;
            if (pidx < Kh) bw = Bp[(size_t)(n0 + row) * Kh + pidx];
            *(u32*)&Bs[row][2 * kp] = bw;
        }
        __syncthreads();

        bf16x8 af = *(const bf16x8*)&As[wv * 16 + lm][quad * 8];
#pragma unroll
        for (int nt = 0; nt < 4; ++nt) {
            bf16x8 bf = *(const bf16x8*)&Bs[nt * 16 + lm][quad * 8];
            acc[nt] = __builtin_amdgcn_mfma_f32_16x16x32_bf16(af, bf, acc[nt], 0, 0, 0);
        }
        __syncthreads();
    }

#pragma unroll
    for (int nt = 0; nt < 4; ++nt) {
#pragma unroll
        for (int r = 0; r < 4; ++r) {
            int m = m0 + wv * 16 + quad * 4 + r;
            if (m >= Msz) continue;
            int n = n0 + nt * 16 + lm;
            float v = acc[nt][r] + bias1[n] + (bias2 ? bias2[n] : 0.f);
            if (relu) v = fmaxf(v, 0.f);
            if (cmode == 0) {
                Cf[(size_t)m * ldc + n] = v;
            } else if (cmode == 1) {
                int b = m / L_, t = m - b * L_;
                Cf[((size_t)(b * 128 + n)) * L_ + t] = v;
            } else if (cmode == 2) {
                int b = m / L_, t = m - b * L_;
                Cf[((size_t)(t * 8 + b)) * ldc + n] = v;
            } else {
                Cb[(size_t)m * ldc + n] = (u16)f2bf_rne(v);
            }
        }
    }
}

// ======================= fused q/k/cnt projection GEMM (bf16 h1b A, packed B) ==================
__global__ __launch_bounds__(256) void gemm_qkv(
    const u16* __restrict__ h1b,
    const u32* __restrict__ qwp, const u32* __restrict__ kwp, const u32* __restrict__ cwp,
    const float* __restrict__ qb, const float* __restrict__ kb, const float* __restrict__ cb,
    float* __restrict__ qo, float* __restrict__ ko, float* __restrict__ co)
{
    __shared__ u16 As[64][40];
    __shared__ u16 Bs[64][40];

    int tid = threadIdx.x;
    int which = blockIdx.y >> 3;
    int m0 = blockIdx.x * 64, n0 = (blockIdx.y & 7) * 64;
    const u32* Bp = which == 0 ? qwp : (which == 1 ? kwp : cwp);
    const float* bias = which == 0 ? qb : (which == 1 ? kb : cb);
    float* Cf = which == 0 ? qo : (which == 1 ? ko : co);

    int wv = tid >> 6, lane = tid & 63;
    int lm = lane & 15, quad = lane >> 4;
    int kp = tid & 15, rw = tid >> 4;

    f32x4 acc[4];
#pragma unroll
    for (int nt = 0; nt < 4; ++nt)
#pragma unroll
        for (int r = 0; r < 4; ++r) acc[nt][r] = 0.f;

    for (int k0 = 0; k0 < 512; k0 += 32) {
#pragma unroll
        for (int i = 0; i < 4; ++i) {
            int row = rw + 16 * i;
            int k = k0 + 2 * kp;
            int m = m0 + row;
            u32 aw = 0;
            if (m < M_) {
                int b = m / L_, t = m - b * L_;
                aw = *(const u32*)(h1b + ((size_t)(t * 8 + b)) * 512 + k);
            }
            *(u32*)&As[row][2 * kp] = aw;
            *(u32*)&Bs[row][2 * kp] = Bp[(size_t)(n0 + row) * 256 + (k0 >> 1) + kp];
        }
        __syncthreads();

        bf16x8 af = *(const bf16x8*)&As[wv * 16 + lm][quad * 8];
#pragma unroll
        for (int nt = 0; nt < 4; ++nt) {
            bf16x8 bf = *(const bf16x8*)&Bs[nt * 16 + lm][quad * 8];
            acc[nt] = __builtin_amdgcn_mfma_f32_16x16x32_bf16(af, bf, acc[nt], 0, 0, 0);
        }
        __syncthreads();
    }

#pragma unroll
    for (int nt = 0; nt < 4; ++nt) {
#pragma unroll
        for (int r = 0; r < 4; ++r) {
            int m = m0 + wv * 16 + quad * 4 + r;
            if (m >= M_) continue;
            int n = n0 + nt * 16 + lm;
            Cf[(size_t)m * 512 + n] = acc[nt][r] + bias[n];
        }
    }
}

// ======================= subject embedding concat (bf16) =======================
__global__ __launch_bounds__(256) void emb_kernel(const float* __restrict__ semb,
                                                  const int* __restrict__ subj,
                                                  u16* __restrict__ x2b)
{
    int idx = blockIdx.x * 256 + threadIdx.x;
    if (idx >= M_ * 64) return;
    int m = idx >> 6, e = idx & 63;
    int b = m / L_;
    x2b[(size_t)m * CE_ + 512 + e] = (u16)f2bf_rne(semb[subj[b] * 64 + e]);
}

// ======================= generic weight pack: fp32 [N][K] -> bf16 pairs [N][K/2] ================
__global__ __launch_bounds__(256) void pack_b(const float* __restrict__ W, u32* __restrict__ P,
                                              int N, int K)
{
    int gid = blockIdx.x * 256 + threadIdx.x;
    int Kh = K >> 1;
    if (gid >= N * Kh) return;
    int n = gid / Kh, p = gid - n * Kh;
    int k = 2 * p;
    u32 lo = f2bf_rne(W[(size_t)n * K + k]);
    u32 hi = f2bf_rne(W[(size_t)n * K + k + 1]);
    P[gid] = lo | (hi << 16);
}

// ======================= fused post-weight pack: qw/kw/cw/fcw (512x512) + outw (128x512) ========
__global__ __launch_bounds__(256) void pack_post(const float* __restrict__ qw,
                                                 const float* __restrict__ kw,
                                                 const float* __restrict__ cw,
                                                 const float* __restrict__ fcw,
                                                 const float* __restrict__ outw,
                                                 u32* __restrict__ P)
{
    int gid = blockIdx.x * 256 + threadIdx.x;   // 557056 total
    if (gid >= 557056) return;
    const float* W;
    int local;
    if (gid < 524288) {
        int wsel = gid >> 17;
        W = wsel == 0 ? qw : (wsel == 1 ? kw : (wsel == 2 ? cw : fcw));
        local = gid & 131071;
    } else {
        W = outw;
        local = gid - 524288;
    }
    int n = local >> 8, p = local & 255;
    int k = 2 * p;
    u32 lo = f2bf_rne(W[(size_t)n * 512 + k]);
    u32 hi = f2bf_rne(W[(size_t)n * 512 + k + 1]);
    P[gid] = lo | (hi << 16);
}

// ======================= w2 pack with k-reorder: k' = kk*512 + ci =======================
__global__ __launch_bounds__(256) void pack_w2k(const float* __restrict__ W, u32* __restrict__ P)
{
    int gid = blockIdx.x * 256 + threadIdx.x;   // 512*1024
    int n = gid >> 10, p = gid & 1023;
    int kk = p >> 8, ci = (2 * p) & 511;
    u32 lo = f2bf_rne(W[(size_t)n * 2048 + ci * 4 + kk]);
    u32 hi = f2bf_rne(W[(size_t)n * 2048 + ci * 4 + 4 + kk]);
    P[gid] = lo | (hi << 16);
}

// ======================= per-batch LSTM weight pack: Whh0/Wih1/Whh1 ===========================
// Layout: P[((mat*16+seg)*32 + dq)*1024 + tid*4 + e], d = dq*4+e in [0,128)
//   thread tid = (rg<<6)|l owns gate-rows {g*512 + seg*32 + rg*8 + jl} and cols
//   cp<2 -> 4l+2cp ; cp>=2 -> 256+4l+2(cp-2);  d = (jl*4+g)*4+cp
__global__ __launch_bounds__(256) void pack_pb(const float* __restrict__ W0,
                                               const float* __restrict__ W1,
                                               const float* __restrict__ W2,
                                               u32* __restrict__ P)
{
    int gid = blockIdx.x * 256 + threadIdx.x;   // 3*16*32*1024 = 1,572,864
    int mat = gid >> 19;
    int seg = (gid >> 15) & 15;
    int dq  = (gid >> 10) & 31;
    int tq  = gid & 1023;
    int tid = tq >> 2, e = tq & 3;
    int d = dq * 4 + e;
    int l = tid & 63, rg = tid >> 6;
    int jl = d >> 4, g = (d >> 2) & 3, cp = d & 3;
    int row = g * 512 + seg * 32 + rg * 8 + jl;
    int c0 = (cp < 2) ? (4 * l + 2 * cp) : (256 + 4 * l + 2 * (cp - 2));
    const float* W = mat == 0 ? W0 : (mat == 1 ? W1 : W2);
    u32 lo = f2bf_rne(W[(size_t)row * 512 + c0]);
    u32 hi = f2bf_rne(W[(size_t)row * 512 + c0 + 1]);
    P[gid] = lo | (hi << 16);
}

// ======================= persistent 2-layer LSTM, PER-BATCH sync domains =======================
// 256 blocks: bat = bx&7 (XCD-affine under round-robin dispatch), layer = (bx>>3)&1,
// seg = bx>>4 (16 segs x 32 gate-rows-of-j). Each of the 8 batches is an independent
// recurrence -> its own flag set f[layer][bat][t][seg16]. Weights + c-state in registers.
// h exchange = 2KB/step/domain, read directly into registers (no LDS staging).
// ONE __syncthreads per step; agent-scope relaxed atomics for h stores + flags (proven r2).
__global__ __launch_bounds__(256, 1) void lstm_persist(
    const float* __restrict__ pre0,
    const u32* __restrict__ Ppb,
    const float* __restrict__ bih1,
    const float* __restrict__ bhh1,
    float* __restrict__ h0seq,
    float* __restrict__ h1seq,
    u16* __restrict__ h1b,
    u32* __restrict__ f0,
    u32* __restrict__ f1)
{
    const int bx = blockIdx.x;
    const int bat = bx & 7;
    const int layer = (bx >> 3) & 1;
    const int seg = bx >> 4;
    const int tid = threadIdx.x;
    const int l = tid & 63;
    const int rg = tid >> 6;

    __shared__ float gates[128];

    // ---- weights once into registers (static-indexed arrays) ----
    const u32* Pm = Ppb + (size_t)((layer ? 2 : 0) * 16 + seg) * 32768;
    u32 wra[128];
#pragma unroll
    for (int dq = 0; dq < 32; ++dq)
        *(uint4*)&wra[dq * 4] = *(const uint4*)&Pm[dq * 1024 + tid * 4];
    u32 wrb[128];
    if (layer) {
        const u32* Pb = Ppb + (size_t)(16 + seg) * 32768;
#pragma unroll
        for (int dq = 0; dq < 32; ++dq)
            *(uint4*)&wrb[dq * 4] = *(const uint4*)&Pb[dq * 1024 + tid * 4];
    }

    // writer-lane constants (lanes l<32 of each wave): slot (g=l&3, jidx=rg*8+(l>>2))
    const int prerow = (l & 3) * 512 + seg * 32 + rg * 8 + (l >> 2);
    float biasreg = 0.f;
    if (layer && l < 32) biasreg = bih1[prerow] + bhh1[prerow];

    u32* const fme = layer ? f1 : f0;
    float creg = 0.f;           // c-state for tid<32
    float4 z4 = make_float4(0.f, 0.f, 0.f, 0.f);

    for (int t = 0; t <= L_; ++t) {
        if (layer ? (t == 0) : (t == L_)) continue;
        const int tt = layer ? (t - 1) : t;

        // hoisted (static data): pre / bias for writer lanes
        float preval = 0.f;
        if (l < 32)
            preval = layer ? biasreg
                           : pre0[((size_t)(tt * 8 + bat)) * 2048 + prerow];

        // ---- poll producers (every wave polls independently; no staging barrier) ----
        const u32* slot = nullptr;
        if (layer) {
            if (l < 16) slot = f0 + (((size_t)(bat * 514 + tt)) << 4) + l;
            else if (l < 32 && tt > 0) slot = f1 + (((size_t)(bat * 514 + tt - 1)) << 4) + (l - 16);
        } else if (tt > 0) {
            if (l < 16) slot = f0 + (((size_t)(bat * 514 + tt - 1)) << 4) + l;
        }
        if (slot) {
            while (__hip_atomic_load(slot, __ATOMIC_RELAXED, __HIP_MEMORY_SCOPE_AGENT) == 0u)
                __builtin_amdgcn_s_sleep(2);
        }
        asm volatile("" ::: "memory");   // compiler fence: keep h loads below the poll

        // ---- h vectors straight into registers (first-touch addresses -> fresh) ----
        float4 hv0 = z4, hv1 = z4, gv0 = z4, gv1 = z4;
        if (tt > 0) {
            const float4* hp = (const float4*)((layer ? h1seq : h0seq)
                                               + ((size_t)((tt - 1) * 8 + bat)) * 512);
            hv0 = hp[l]; hv1 = hp[l + 64];
        }
        if (layer) {
            const float4* gp = (const float4*)(h0seq + ((size_t)(tt * 8 + bat)) * 512);
            gv0 = gp[l]; gv1 = gp[l + 64];
        }

        float acc[32];
#pragma unroll
        for (int a = 0; a < 32; ++a) acc[a] = 0.f;

#pragma unroll
        for (int jl = 0; jl < 8; ++jl)
#pragma unroll
            for (int g = 0; g < 4; ++g) {
                const int ix = (jl * 4 + g) * 4;
                float s = acc[jl * 4 + g];
                u32 w;
                w = wra[ix + 0]; s = fmaf(__uint_as_float(w << 16), hv0.x, s); s = fmaf(__uint_as_float(w & 0xffff0000u), hv0.y, s);
                w = wra[ix + 1]; s = fmaf(__uint_as_float(w << 16), hv0.z, s); s = fmaf(__uint_as_float(w & 0xffff0000u), hv0.w, s);
                w = wra[ix + 2]; s = fmaf(__uint_as_float(w << 16), hv1.x, s); s = fmaf(__uint_as_float(w & 0xffff0000u), hv1.y, s);
                w = wra[ix + 3]; s = fmaf(__uint_as_float(w << 16), hv1.z, s); s = fmaf(__uint_as_float(w & 0xffff0000u), hv1.w, s);
                acc[jl * 4 + g] = s;
            }
        if (layer) {
#pragma unroll
            for (int jl = 0; jl < 8; ++jl)
#pragma unroll
                for (int g = 0; g < 4; ++g) {
                    const int ix = (jl * 4 + g) * 4;
                    float s = acc[jl * 4 + g];
                    u32 w;
                    w = wrb[ix + 0]; s = fmaf(__uint_as_float(w << 16), gv0.x, s); s = fmaf(__uint_as_float(w & 0xffff0000u), gv0.y, s);
                    w = wrb[ix + 1]; s = fmaf(__uint_as_float(w << 16), gv0.z, s); s = fmaf(__uint_as_float(w & 0xffff0000u), gv0.w, s);
                    w = wrb[ix + 2]; s = fmaf(__uint_as_float(w << 16), gv1.x, s); s = fmaf(__uint_as_float(w & 0xffff0000u), gv1.y, s);
                    w = wrb[ix + 3]; s = fmaf(__uint_as_float(w << 16), gv1.z, s); s = fmaf(__uint_as_float(w & 0xffff0000u), gv1.w, s);
                    acc[jl * 4 + g] = s;
                }
        }

        // ---- full 64-lane butterfly reduce on 32 accumulators ----
#pragma unroll
        for (int m = 1; m <= 32; m <<= 1)
#pragma unroll
            for (int a = 0; a < 32; ++a)
                acc[a] += __shfl_xor(acc[a], m);

        // static select tree: lane l extracts acc[l&31]
        float s16[16];
#pragma unroll
        for (int i = 0; i < 16; ++i) s16[i] = (l & 1) ? acc[2 * i + 1] : acc[2 * i];
        float s8[8];
#pragma unroll
        for (int i = 0; i < 8; ++i) s8[i] = (l & 2) ? s16[2 * i + 1] : s16[2 * i];
        float s4[4];
#pragma unroll
        for (int i = 0; i < 4; ++i) s4[i] = (l & 4) ? s8[2 * i + 1] : s8[2 * i];
        float s2[2];
#pragma unroll
        for (int i = 0; i < 2; ++i) s2[i] = (l & 8) ? s4[2 * i + 1] : s4[2 * i];
        float s1 = (l & 16) ? s2[1] : s2[0];

        if (l < 32)
            gates[(l & 3) * 32 + rg * 8 + (l >> 2)] = s1 + preval;
        __syncthreads();

        float hstore = 0.f;
        if (tid < 32) {
            float gi = gates[tid];
            float gf = gates[32 + tid];
            float gg = gates[64 + tid];
            float go = gates[96 + tid];
            float cprev = (tt == 0) ? 0.f : creg;
            float si = 1.f / (1.f + expf(-gi));
            float sf = 1.f / (1.f + expf(-gf));
            float so = 1.f / (1.f + expf(-go));
            float cn = sf * cprev + si * tanhf(gg);
            creg = cn;
            hstore = so * tanhf(cn);
            float* hout = layer ? h1seq : h0seq;
            __hip_atomic_store(&hout[((size_t)(tt * 8 + bat)) * 512 + seg * 32 + tid], hstore,
                               __ATOMIC_RELAXED, __HIP_MEMORY_SCOPE_AGENT);
        }
        if (tid < 64) { asm volatile("s_waitcnt vmcnt(0)" ::: "memory"); }
        if (tid == 0)
            __hip_atomic_store(fme + (((size_t)(bat * 514 + tt)) << 4) + seg, 1u,
                               __ATOMIC_RELAXED, __HIP_MEMORY_SCOPE_AGENT);
        if (layer && tid < 32)
            h1b[((size_t)(tt * 8 + bat)) * 512 + seg * 32 + tid] = (u16)f2bf_rne(hstore);
        // no end barrier needed: gates[] reuse at t+1 is gated by own-seg flag via the poll
    }
}

// ======================= banded attention (radius 50), bf16 out =======================
__global__ __launch_bounds__(128) void attn_kernel(const float* __restrict__ q,
                                                   const float* __restrict__ k,
                                                   const float* __restrict__ cnt,
                                                   const float* __restrict__ rel,
                                                   u16* __restrict__ outb)
{
    int t = blockIdx.x, h = blockIdx.y, b = blockIdx.z;
    int s_lo = max(0, t - R_), s_hi = min(L_ - 1, t + R_);
    int W = s_hi - s_lo + 1;
    int tid = threadIdx.x;

    __shared__ float qrow[64];
    __shared__ float dots[104];
    __shared__ float red[128];

    const float* qp = q + ((size_t)(b * L_ + t) * C_ + h * D_);
    if (tid < 64) qrow[tid] = qp[tid];
    __syncthreads();

    if (tid < W) {
        int s = s_lo + tid;
        const float* kp = k + ((size_t)(b * L_ + s) * C_ + h * D_);
        const float* rp = rel + (R_ + t - s) * D_;
        float acc = 0.f;
#pragma unroll 8
        for (int d = 0; d < 64; ++d)
            acc += qrow[d] * (kp[d] + 0.3f * rp[d]);
        dots[tid] = acc;
    }
    __syncthreads();

    red[tid] = (tid < W) ? dots[tid] : -INFINITY;
    __syncthreads();
    for (int s = 64; s > 0; s >>= 1) {
        if (tid < s) red[tid] = fmaxf(red[tid], red[tid + s]);
        __syncthreads();
    }
    float mx = red[0];
    __syncthreads();
    float e = 0.f;
    if (tid < W) { e = expf(dots[tid] - mx); dots[tid] = e; }
    red[tid] = e;
    __syncthreads();
    for (int s = 64; s > 0; s >>= 1) {
        if (tid < s) red[tid] += red[tid + s];
        __syncthreads();
    }
    float inv = 1.f / red[0];
    if (tid < W) dots[tid] *= inv;
    __syncthreads();

    if (tid < 64) {
        float acc = 0.f;
        const float* cb = cnt + ((size_t)(b * L_ + s_lo) * C_ + h * D_ + tid);
        const float* rb = rel + (R_ + t - s_lo) * D_ + tid;
        for (int i = 0; i < W; ++i)
            acc += dots[i] * (cb[(size_t)i * C_] + 0.3f * rb[-i * D_]);
        outb[(size_t)(b * L_ + t) * C_ + h * D_ + tid] = (u16)f2bf_rne(acc);
    }
}

// ======================= BatchNorm sums (coalesced, atomic) =======================
__global__ __launch_bounds__(512) void bn_sum(const float* __restrict__ fcout, float* __restrict__ stats)
{
    int c = threadIdx.x;
    float s = 0.f, ss = 0.f;
    for (int m = blockIdx.x; m < M_; m += 32) {
        float v = fcout[(size_t)m * 512 + c];
        s += v; ss += v * v;
    }
    atomicAdd(&stats[c], s);
    atomicAdd(&stats[512 + c], ss);
}

// ======================= BN apply + ReLU*scale + residual -> bf16 xfin =======================
__global__ __launch_bounds__(256) void bn_apply(const float* __restrict__ fcout,
                                                const float* __restrict__ stats,
                                                const float* __restrict__ bng, const float* __restrict__ bnb,
                                                const float* __restrict__ ascl,
                                                const float* __restrict__ h1tm,
                                                u16* __restrict__ xfinb)
{
    int idx = blockIdx.x * 256 + threadIdx.x;
    if (idx >= M_ * 512) return;
    int c = idx & 511;
    int m = idx >> 9;
    int b = m / L_, t = m - b * L_;
    float mean = stats[c] * (1.f / (float)M_);
    float var = stats[512 + c] * (1.f / (float)M_) - mean * mean;
    float rs = rsqrtf(fmaxf(var, 0.f) + 1e-5f);
    float v = (fcout[idx] - mean) * rs * bng[c] + bnb[c];
    v = fmaxf(v, 0.f) * ascl[c];
    xfinb[idx] = (u16)f2bf_rne(h1tm[((size_t)(t * 8 + b)) * 512 + c] + v);
}

// ======================= host launch =======================
extern "C" void kernel_launch(void* const* d_in, const int* in_sizes, int n_in,
                              void* d_out, int out_size, void* d_ws, size_t ws_size,
                              hipStream_t stream)
{
    const float* meg  = (const float*)d_in[0];
    const float* w1   = (const float*)d_in[1];
    const float* b1   = (const float*)d_in[2];
    const float* w2   = (const float*)d_in[3];
    const float* b2   = (const float*)d_in[4];
    const float* semb = (const float*)d_in[5];
    const float* Wih0 = (const float*)d_in[6];
    const float* Whh0 = (const float*)d_in[7];
    const float* bih0 = (const float*)d_in[8];
    const float* bhh0 = (const float*)d_in[9];
    const float* Wih1 = (const float*)d_in[10];
    const float* Whh1 = (const float*)d_in[11];
    const float* bih1 = (const float*)d_in[12];
    const float* bhh1 = (const float*)d_in[13];
    const float* qw   = (const float*)d_in[14];
    const float* qb   = (const float*)d_in[15];
    const float* kw   = (const float*)d_in[16];
    const float* kb   = (const float*)d_in[17];
    const float* cw   = (const float*)d_in[18];
    const float* cbi  = (const float*)d_in[19];
    const float* rel  = (const float*)d_in[20];
    const float* fcw  = (const float*)d_in[21];
    const float* fcb  = (const float*)d_in[22];
    const float* bng  = (const float*)d_in[23];
    const float* bnb  = (const float*)d_in[24];
    const float* ascl = (const float*)d_in[25];
    const float* outw = (const float*)d_in[26];
    const float* outb = (const float*)d_in[27];
    const int* subj = (const int*)d_in[28];
    float* out = (float*)d_out;

    float* ws = (float*)d_ws;
    // ---- arena (float-slot offsets), phase-overlaid ----
    // conv phase:
    u16*   x1b   = (u16*)(ws + 0);          // [8200][512] bf16
    u32*   w1p   = (u32*)(ws + 6562304);    // 512x546
    u32*   w2p   = (u32*)(ws + 6841856);    // 512x1024
    u16*   x2b   = (u16*)(ws + 4198400);    // [4104][576] bf16
    u32*   wih0p = (u32*)(ws + 14967296);   // 2048x288
    // LSTM phase:
    u32*   P0    = (u32*)(ws + 0);          // packed per-batch LSTM weights (pack_pb), 1.5M words
    u32*   flg   = (u32*)(ws + 1572864);    // f0[8][514][16] | f1[8][514][16]
    float* pre0  = ws + 6562304;            // [(t*8+b)][2048] fp32
    float* h0    = ws + 14967296;           // [t][b][c] fp32
    float* h1    = ws + 17068544;
    u16*   h1b   = (u16*)(ws + 19169792);   // bf16 mirror
    // post-LSTM phase:
    float* qb_f  = ws + 0;
    float* kb_f  = ws + 2101248;
    float* cb_f  = ws + 4202496;
    u16*   attno = (u16*)(ws + 6562304);    // bf16, over dead pre0
    float* fco   = ws + 8663552;
    float* stats = ws + 10764800;
    u32*   qwp   = (u32*)(ws + 10765824);   // contiguous: qwp|kwp|cwp|fcwp|outwp
    u32*   kwp   = (u32*)(ws + 10896896);
    u32*   cwp   = (u32*)(ws + 11027968);
    u32*   fcwp  = (u32*)(ws + 11159040);
    u32*   outwp = (u32*)(ws + 11290112);
    u16*   xfinb = (u16*)(ws + 19169792);   // bf16, overwrites dead h1b

    auto gemm = [&](const void* A, const u32* Bp, const float* bi1, const float* bi2,
                    float* Cf, u16* Cb, int Msz, int Nsz, int Ksz,
                    int lda, int ldc, int amode, int cmode, int relu) {
        dim3 g((Msz + 63) / 64, Nsz / 64);
        gemm_kernel<<<g, 256, 0, stream>>>(A, Bp, bi1, bi2, Cf, Cb,
                                           Msz, Nsz, Ksz, lda, ldc, amode, cmode, relu);
    };

    // ---- pack conv weights ----
    pack_b<<<(512 * 546 + 255) / 256, 256, 0, stream>>>(w1, w1p, 512, 1092);
    pack_w2k<<<2048, 256, 0, stream>>>(w2, w2p);

    // conv1 -> x1b bf16 [b*1025+t][512], relu
    gemm(meg, w1p, b1, nullptr, nullptr, x1b, M1_, 512, K1_, 0, 512, 2, 3, 1);
    // conv2 -> x2b bf16 [b*513+t][576] cols 0..511, relu
    gemm(x1b, w2p, b2, nullptr, nullptr, x2b, M_, 512, 2048, 0, CE_, 5, 3, 1);
    // subject embedding bf16 -> cols 512..575
    emb_kernel<<<(M_ * 64 + 255) / 256, 256, 0, stream>>>(semb, subj, x2b);

    // ---- pack LSTM (per-batch layout) + pre0 weights ----
    pack_pb<<<6144, 256, 0, stream>>>(Whh0, Wih1, Whh1, P0);
    pack_b<<<(2048 * 288 + 255) / 256, 256, 0, stream>>>(Wih0, wih0p, 2048, 576);

    // layer-0 x-projection (bf16 A, packed B, time-major fp32 out, both biases)
    gemm(x2b, wih0p, bih0, bhh0, pre0, nullptr, M_, 2048, CE_, CE_, 2048, 6, 2, 0);

    // persistent fused 2-layer LSTM: ONE launch, 8 independent per-batch domains
    hipMemsetAsync(flg, 0, 2 * 8 * 514 * 16 * sizeof(u32), stream);
    lstm_persist<<<dim3(256), 256, 0, stream>>>(pre0, P0, bih1, bhh1,
                                                h0, h1, h1b, flg, flg + 8 * 514 * 16);

    // ---- pack post weights (one launch) + zero bn stats ----
    pack_post<<<(557056 + 255) / 256, 256, 0, stream>>>(qw, kw, cw, fcw, outw, qwp);
    hipMemsetAsync(stats, 0, 1024 * sizeof(float), stream);

    // fused q/k/cnt projections (bf16 h1b)
    gemm_qkv<<<dim3((M_ + 63) / 64, 24), 256, 0, stream>>>(h1b, qwp, kwp, cwp, qb, kb, cbi,
                                                           qb_f, kb_f, cb_f);

    attn_kernel<<<dim3(L_, H_, B_), 128, 0, stream>>>(qb_f, kb_f, cb_f, rel, attno);

    // fc (bf16 attno A) + BN(train) + relu*scale + residual -> xfinb bf16
    gemm(attno, fcwp, fcb, nullptr, fco, nullptr, M_, 512, 512, 512, 512, 6, 0, 0);
    bn_sum<<<32, 512, 0, stream>>>(fco, stats);
    bn_apply<<<(M_ * 512 + 255) / 256, 256, 0, stream>>>(fco, stats, bng, bnb, ascl, h1, xfinb);

    // final projection -> d_out [b][128][t] fp32 (bf16 xfin A)
    gemm(xfinb, outwp, outb, nullptr, out, nullptr, M_, 128, 512, 512, 0, 6, 1, 0);
}

// Round 4
// 5066.208 us; speedup vs baseline: 1.3909x; 1.3909x over previous
//
#include <hip/hip_runtime.h>
#include <cstdint>
#include <cmath>

typedef unsigned short u16;
typedef unsigned int u32;
typedef __attribute__((ext_vector_type(8))) short bf16x8;
typedef __attribute__((ext_vector_type(4))) float f32x4;

// ---- model dims ----
#define B_    8
#define T_IN  2048
#define CIN1  273
#define L1_   1025
#define L_    513
#define C_    512
#define CE_   576
#define M1_   (B_*L1_)   /* 8200 */
#define M_    (B_*L_)    /* 4104 */
#define K1_   (CIN1*4)   /* 1092 */
#define H_    8
#define D_    64
#define R_    50

__device__ __forceinline__ u32 f2bf_rne(float f) {
    u32 x = __float_as_uint(f);
    return (x + 0x7fffu + ((x >> 16) & 1u)) >> 16;
}

// ======================= A-pair loader: returns packed bf16x2 for (k, k+1), k even ==============
// amode: 2 conv1 im2col from meg (fp32); 5 conv2 im2col from x1b (bf16, k-order kk*512+ci);
//        6 bf16 rowmajor(lda)
__device__ __forceinline__ u32 a_pair(const void* A, int m, int k, int lda, int amode, int Ksz) {
    if (amode == 2) {
        if (k >= K1_) return 0;
        int b = m / L1_, t = m - b * L1_;
        int ci = k >> 2, kk = k & 3;
        int it = 2 * t - 2 + kk;
        const float* mg = (const float*)A + ((size_t)(b * CIN1 + ci)) * T_IN;
        u32 lo = ((unsigned)it < (unsigned)T_IN)       ? f2bf_rne(mg[it])     : 0;
        u32 hi = ((unsigned)(it + 1) < (unsigned)T_IN) ? f2bf_rne(mg[it + 1]) : 0;
        return lo | (hi << 16);
    } else if (amode == 5) {
        int b = m / L_, t = m - b * L_;
        int kk = k >> 9, ci = k & 511;
        int it = 2 * t - 2 + kk;
        if ((unsigned)it >= (unsigned)L1_) return 0;
        return *(const u32*)((const u16*)A + ((size_t)(b * L1_ + it)) * 512 + ci);
    } else {
        return *(const u32*)((const u16*)A + (size_t)m * lda + k);
    }
}

// ======================= MFMA GEMM 64x64 (packed bf16 B) =======================
// cmode: 0 fp32 C[m*ldc+n]; 1 out[b][n][t] (n<128); 2 fp32 [(t*8+b)*ldc+n]; 3 bf16 Cb[m*ldc+n]
__global__ __launch_bounds__(256) void gemm_kernel(
    const void* __restrict__ Aptr, const u32* __restrict__ Bp,
    const float* __restrict__ bias1, const float* __restrict__ bias2,
    float* __restrict__ Cf, u16* __restrict__ Cb,
    int Msz, int Nsz, int Ksz, int lda, int ldc, int amode, int cmode, int relu)
{
    __shared__ u16 As[64][40];
    __shared__ u16 Bs[64][40];

    int tid = threadIdx.x;
    int m0 = blockIdx.x * 64, n0 = blockIdx.y * 64;
    int wv = tid >> 6, lane = tid & 63;
    int lm = lane & 15, quad = lane >> 4;
    int kp = tid & 15, rw = tid >> 4;
    int Kh = Ksz >> 1;

    f32x4 acc[4];
#pragma unroll
    for (int nt = 0; nt < 4; ++nt)
#pragma unroll
        for (int r = 0; r < 4; ++r) acc[nt][r] = 0.f;

    for (int k0 = 0; k0 < Ksz; k0 += 32) {
        int pidx = (k0 >> 1) + kp;
#pragma unroll
        for (int i = 0; i < 4; ++i) {
            int row = rw + 16 * i;
            int k = k0 + 2 * kp;
            int m = m0 + row;
            u32 aw = 0;
            if (m < Msz && k < Ksz) aw = a_pair(Aptr, m, k, lda, amode, Ksz);
            *(u32*)&As[row][2 * kp] = aw;
            u32 bw = 0;
            if (pidx < Kh) bw = Bp[(size_t)(n0 + row) * Kh + pidx];
            *(u32*)&Bs[row][2 * kp] = bw;
        }
        __syncthreads();

        bf16x8 af = *(const bf16x8*)&As[wv * 16 + lm][quad * 8];
#pragma unroll
        for (int nt = 0; nt < 4; ++nt) {
            bf16x8 bf = *(const bf16x8*)&Bs[nt * 16 + lm][quad * 8];
            acc[nt] = __builtin_amdgcn_mfma_f32_16x16x32_bf16(af, bf, acc[nt], 0, 0, 0);
        }
        __syncthreads();
    }

#pragma unroll
    for (int nt = 0; nt < 4; ++nt) {
#pragma unroll
        for (int r = 0; r < 4; ++r) {
            int m = m0 + wv * 16 + quad * 4 + r;
            if (m >= Msz) continue;
            int n = n0 + nt * 16 + lm;
            float v = acc[nt][r] + bias1[n] + (bias2 ? bias2[n] : 0.f);
            if (relu) v = fmaxf(v, 0.f);
            if (cmode == 0) {
                Cf[(size_t)m * ldc + n] = v;
            } else if (cmode == 1) {
                int b = m / L_, t = m - b * L_;
                Cf[((size_t)(b * 128 + n)) * L_ + t] = v;
            } else if (cmode == 2) {
                int b = m / L_, t = m - b * L_;
                Cf[((size_t)(t * 8 + b)) * ldc + n] = v;
            } else {
                Cb[(size_t)m * ldc + n] = (u16)f2bf_rne(v);
            }
        }
    }
}

// ======================= fused q/k/cnt projection GEMM (bf16 h1b A, packed B) ==================
__global__ __launch_bounds__(256) void gemm_qkv(
    const u16* __restrict__ h1b,
    const u32* __restrict__ qwp, const u32* __restrict__ kwp, const u32* __restrict__ cwp,
    const float* __restrict__ qb, const float* __restrict__ kb, const float* __restrict__ cb,
    float* __restrict__ qo, float* __restrict__ ko, float* __restrict__ co)
{
    __shared__ u16 As[64][40];
    __shared__ u16 Bs[64][40];

    int tid = threadIdx.x;
    int which = blockIdx.y >> 3;
    int m0 = blockIdx.x * 64, n0 = (blockIdx.y & 7) * 64;
    const u32* Bp = which == 0 ? qwp : (which == 1 ? kwp : cwp);
    const float* bias = which == 0 ? qb : (which == 1 ? kb : cb);
    float* Cf = which == 0 ? qo : (which == 1 ? ko : co);

    int wv = tid >> 6, lane = tid & 63;
    int lm = lane & 15, quad = lane >> 4;
    int kp = tid & 15, rw = tid >> 4;

    f32x4 acc[4];
#pragma unroll
    for (int nt = 0; nt < 4; ++nt)
#pragma unroll
        for (int r = 0; r < 4; ++r) acc[nt][r] = 0.f;

    for (int k0 = 0; k0 < 512; k0 += 32) {
#pragma unroll
        for (int i = 0; i < 4; ++i) {
            int row = rw + 16 * i;
            int k = k0 + 2 * kp;
            int m = m0 + row;
            u32 aw = 0;
            if (m < M_) {
                int b = m / L_, t = m - b * L_;
                aw = *(const u32*)(h1b + ((size_t)(t * 8 + b)) * 512 + k);
            }
            *(u32*)&As[row][2 * kp] = aw;
            *(u32*)&Bs[row][2 * kp] = Bp[(size_t)(n0 + row) * 256 + (k0 >> 1) + kp];
        }
        __syncthreads();

        bf16x8 af = *(const bf16x8*)&As[wv * 16 + lm][quad * 8];
#pragma unroll
        for (int nt = 0; nt < 4; ++nt) {
            bf16x8 bf = *(const bf16x8*)&Bs[nt * 16 + lm][quad * 8];
            acc[nt] = __builtin_amdgcn_mfma_f32_16x16x32_bf16(af, bf, acc[nt], 0, 0, 0);
        }
        __syncthreads();
    }

#pragma unroll
    for (int nt = 0; nt < 4; ++nt) {
#pragma unroll
        for (int r = 0; r < 4; ++r) {
            int m = m0 + wv * 16 + quad * 4 + r;
            if (m >= M_) continue;
            int n = n0 + nt * 16 + lm;
            Cf[(size_t)m * 512 + n] = acc[nt][r] + bias[n];
        }
    }
}

// ======================= subject embedding concat (bf16) =======================
__global__ __launch_bounds__(256) void emb_kernel(const float* __restrict__ semb,
                                                  const int* __restrict__ subj,
                                                  u16* __restrict__ x2b)
{
    int idx = blockIdx.x * 256 + threadIdx.x;
    if (idx >= M_ * 64) return;
    int m = idx >> 6, e = idx & 63;
    int b = m / L_;
    x2b[(size_t)m * CE_ + 512 + e] = (u16)f2bf_rne(semb[subj[b] * 64 + e]);
}

// ======================= generic weight pack: fp32 [N][K] -> bf16 pairs [N][K/2] ================
__global__ __launch_bounds__(256) void pack_b(const float* __restrict__ W, u32* __restrict__ P,
                                              int N, int K)
{
    int gid = blockIdx.x * 256 + threadIdx.x;
    int Kh = K >> 1;
    if (gid >= N * Kh) return;
    int n = gid / Kh, p = gid - n * Kh;
    int k = 2 * p;
    u32 lo = f2bf_rne(W[(size_t)n * K + k]);
    u32 hi = f2bf_rne(W[(size_t)n * K + k + 1]);
    P[gid] = lo | (hi << 16);
}

// ======================= fused post-weight pack: qw/kw/cw/fcw (512x512) + outw (128x512) ========
__global__ __launch_bounds__(256) void pack_post(const float* __restrict__ qw,
                                                 const float* __restrict__ kw,
                                                 const float* __restrict__ cw,
                                                 const float* __restrict__ fcw,
                                                 const float* __restrict__ outw,
                                                 u32* __restrict__ P)
{
    int gid = blockIdx.x * 256 + threadIdx.x;   // 557056 total
    if (gid >= 557056) return;
    const float* W;
    int local;
    if (gid < 524288) {
        int wsel = gid >> 17;
        W = wsel == 0 ? qw : (wsel == 1 ? kw : (wsel == 2 ? cw : fcw));
        local = gid & 131071;
    } else {
        W = outw;
        local = gid - 524288;
    }
    int n = local >> 8, p = local & 255;
    int k = 2 * p;
    u32 lo = f2bf_rne(W[(size_t)n * 512 + k]);
    u32 hi = f2bf_rne(W[(size_t)n * 512 + k + 1]);
    P[gid] = lo | (hi << 16);
}

// ======================= w2 pack with k-reorder: k' = kk*512 + ci =======================
__global__ __launch_bounds__(256) void pack_w2k(const float* __restrict__ W, u32* __restrict__ P)
{
    int gid = blockIdx.x * 256 + threadIdx.x;   // 512*1024
    int n = gid >> 10, p = gid & 1023;
    int kk = p >> 8, ci = (2 * p) & 511;
    u32 lo = f2bf_rne(W[(size_t)n * 2048 + ci * 4 + kk]);
    u32 hi = f2bf_rne(W[(size_t)n * 2048 + ci * 4 + 4 + kk]);
    P[gid] = lo | (hi << 16);
}

// ======================= fused LSTM weight pack: Whh0/Wih1/Whh1 in one launch ===================
__global__ __launch_bounds__(256) void pack_w3(const float* __restrict__ W0,
                                               const float* __restrict__ W1,
                                               const float* __restrict__ W2,
                                               u32* __restrict__ P)   // P0|P1|P2 contiguous
{
    int gid3 = blockIdx.x * 256 + threadIdx.x;  // 3*524288
    int src = gid3 >> 19;
    int gid = gid3 & 524287;
    const float* W = src == 0 ? W0 : (src == 1 ? W1 : W2);
    int r = gid & 1, lane = (gid >> 1) & 63, i2 = (gid >> 7) & 1;
    int g = (gid >> 8) & 3, j = gid >> 10;
    int row = g * 512 + j;
    int c0 = 4 * (lane + 64 * i2) + 2 * r;
    u32 lo = f2bf_rne(W[(size_t)row * 512 + c0]);
    u32 hi = f2bf_rne(W[(size_t)row * 512 + c0 + 1]);
    P[gid3] = lo | (hi << 16);
}

// ======================= persistent fused 2-layer LSTM (r2 structure, leaner per-step path) ====
// One launch for all 513 steps. 256 blocks (0-127: layer 0, 128-255: layer 1, skewed one step).
// Weights + c-state in registers for the whole sequence (r2 layout: 124 VGPR, NO per-batch
// weight replication -- r3's spill lesson). Per-step path vs r2:
//   - h loads go STRAIGHT into registers (no LDS staging, no staging barrier)
//   - ALL waves poll the producer slots independently (no poll barrier / wake)
//   - no end-of-loop barrier (part[]/gates[] reuse is ordered by the two reduce barriers)
// Sync protocol unchanged from r2 (proven): relaxed agent atomics for h + per-block flag slots,
// publish after s_waitcnt vmcnt(0); consumers read h with normal first-touch loads.
__global__ __launch_bounds__(256, 1) void lstm_persist(
    const float* __restrict__ pre0,
    const u32* __restrict__ P0,
    const u32* __restrict__ P1,
    const u32* __restrict__ P2,
    const float* __restrict__ bih1,
    const float* __restrict__ bhh1,
    float* __restrict__ h0seq,
    float* __restrict__ h1seq,
    u16* __restrict__ h1b,
    u32* __restrict__ f0,
    u32* __restrict__ f1)
{
    const int layer = blockIdx.x >> 7;
    const int blk = blockIdx.x & 127;
    const int tid = threadIdx.x;
    const int l = tid & 63;
    const int rg = tid >> 6;
    const int j = blk * 4 + rg;

    __shared__ float part[4 * 8 * 33];
    __shared__ float gates[4 * 33];

    // ---- weights once into registers (r2/pack_w3 layout) ----
    const u32* wA = (layer ? P2 : P0) + (size_t)j * 1024;
    uint2 wra[8], wrb[8];
#pragma unroll
    for (int i2 = 0; i2 < 2; ++i2)
#pragma unroll
        for (int g = 0; g < 4; ++g)
            wra[i2 * 4 + g] = *(const uint2*)&wA[(g * 2 + i2) * 128 + l * 2];
    if (layer) {
        const u32* wB = P1 + (size_t)j * 1024;
#pragma unroll
        for (int i2 = 0; i2 < 2; ++i2)
#pragma unroll
            for (int g = 0; g < 4; ++g)
                wrb[i2 * 4 + g] = *(const uint2*)&wB[(g * 2 + i2) * 128 + l * 2];
    }

    // per-thread constants for the gate assembly phase
    int fb = 0, grow = 0;
    float bias1 = 0.f;
    if (tid < 128) {
        int fw = tid >> 5;
        fb = tid & 7;
        grow = ((tid & 31) >> 3) * 512 + blk * 4 + fw;
        if (layer) bias1 = bih1[grow] + bhh1[grow];   // layer-1 pre is step-invariant
    }

    float creg = 0.f;   // c-state (tid<32), registers across steps
    const float4 z4 = make_float4(0.f, 0.f, 0.f, 0.f);

    for (int t = 0; t <= L_; ++t) {
        bool active = layer ? (t >= 1) : (t < L_);
        if (!active) continue;
        int tt = layer ? (t - 1) : t;

        // hoist pre0 load (flag-independent) to overlap the poll
        float mypre = 0.f;
        if (tid < 128)
            mypre = layer ? bias1 : pre0[((size_t)(tt * 8 + fb)) * 2048 + grow];

        // ---- every wave polls producers independently (no barrier) ----
        {
            const u32* sA = nullptr;
            const u32* sB = nullptr;
            if (layer) {
                sA = f0 + (size_t)tt * 128;
                if (tt > 0) sB = f1 + (size_t)(tt - 1) * 128;
            } else if (tt > 0) {
                sA = f0 + (size_t)(tt - 1) * 128;
            }
            if (sA) {
                bool a0 = false, a1 = false;
                bool b0 = (sB == nullptr), b1 = (sB == nullptr);
                for (;;) {
                    if (!a0) a0 = __hip_atomic_load(&sA[l], __ATOMIC_RELAXED, __HIP_MEMORY_SCOPE_AGENT) != 0u;
                    if (!a1) a1 = __hip_atomic_load(&sA[l + 64], __ATOMIC_RELAXED, __HIP_MEMORY_SCOPE_AGENT) != 0u;
                    if (sB) {
                        if (!b0) b0 = __hip_atomic_load(&sB[l], __ATOMIC_RELAXED, __HIP_MEMORY_SCOPE_AGENT) != 0u;
                        if (!b1) b1 = __hip_atomic_load(&sB[l + 64], __ATOMIC_RELAXED, __HIP_MEMORY_SCOPE_AGENT) != 0u;
                    }
                    if (__all(a0 && a1 && b0 && b1)) break;
                    __builtin_amdgcn_s_sleep(1);
                }
            }
        }
        asm volatile("" ::: "memory");   // keep h loads below the poll

        // ---- h fragments straight into registers + FMA ----
        float acc[4][8];
#pragma unroll
        for (int g = 0; g < 4; ++g)
#pragma unroll
            for (int b = 0; b < 8; ++b) acc[g][b] = 0.f;

        const float* hsrcA = layer ? h1seq : h0seq;
#pragma unroll
        for (int i2 = 0; i2 < 2; ++i2) {
            int cq = l + 64 * i2;
            float4 hv[8];
            if (tt > 0) {
                const float4* hp = (const float4*)(hsrcA + (size_t)(tt - 1) * 4096);
#pragma unroll
                for (int b = 0; b < 8; ++b) hv[b] = hp[b * 128 + cq];
            } else {
#pragma unroll
                for (int b = 0; b < 8; ++b) hv[b] = z4;
            }
#pragma unroll
            for (int g = 0; g < 4; ++g) {
                uint2 ww = wra[i2 * 4 + g];
                float w0 = __uint_as_float(ww.x << 16);
                float w1 = __uint_as_float(ww.x & 0xffff0000u);
                float w2 = __uint_as_float(ww.y << 16);
                float w3 = __uint_as_float(ww.y & 0xffff0000u);
#pragma unroll
                for (int b = 0; b < 8; ++b)
                    acc[g][b] = fmaf(w0, hv[b].x, fmaf(w1, hv[b].y,
                                fmaf(w2, hv[b].z, fmaf(w3, hv[b].w, acc[g][b]))));
            }
        }
        if (layer) {
            const float4* gp = (const float4*)(h0seq + (size_t)tt * 4096);
#pragma unroll
            for (int i2 = 0; i2 < 2; ++i2) {
                int cq = l + 64 * i2;
                float4 hv[8];
#pragma unroll
                for (int b = 0; b < 8; ++b) hv[b] = gp[b * 128 + cq];
#pragma unroll
                for (int g = 0; g < 4; ++g) {
                    uint2 ww = wrb[i2 * 4 + g];
                    float w0 = __uint_as_float(ww.x << 16);
                    float w1 = __uint_as_float(ww.x & 0xffff0000u);
                    float w2 = __uint_as_float(ww.y << 16);
                    float w3 = __uint_as_float(ww.y & 0xffff0000u);
#pragma unroll
                    for (int b = 0; b < 8; ++b)
                        acc[g][b] = fmaf(w0, hv[b].x, fmaf(w1, hv[b].y,
                                    fmaf(w2, hv[b].z, fmaf(w3, hv[b].w, acc[g][b]))));
                }
            }
        }

#pragma unroll
        for (int m = 8; m <= 32; m <<= 1)
#pragma unroll
            for (int g = 0; g < 4; ++g)
#pragma unroll
                for (int b = 0; b < 8; ++b)
                    acc[g][b] += __shfl_xor(acc[g][b], m);
        if (l < 8) {
#pragma unroll
            for (int g = 0; g < 4; ++g)
#pragma unroll
                for (int b = 0; b < 8; ++b)
                    part[(rg * 8 + l) * 33 + g * 8 + b] = acc[g][b];
        }
        __syncthreads();

        if (tid < 128) {
            int w = tid >> 5, x = tid & 31;
            float s = 0.f;
#pragma unroll
            for (int p = 0; p < 8; ++p) s += part[(w * 8 + p) * 33 + x];
            gates[w * 33 + x] = s + mypre;
        }
        __syncthreads();

        float hstore = 0.f;
        if (tid < 32) {
            int w = tid >> 3, b = tid & 7;
            float gi = gates[w * 33 + 0 * 8 + b];
            float gf = gates[w * 33 + 1 * 8 + b];
            float gg = gates[w * 33 + 2 * 8 + b];
            float go = gates[w * 33 + 3 * 8 + b];
            int ji = blk * 4 + w;
            float cprev = (tt == 0) ? 0.f : creg;
            float si = 1.f / (1.f + expf(-gi));
            float sf = 1.f / (1.f + expf(-gf));
            float so = 1.f / (1.f + expf(-go));
            float cn = sf * cprev + si * tanhf(gg);
            creg = cn;
            hstore = so * tanhf(cn);
            float* hout = layer ? h1seq : h0seq;
            __hip_atomic_store(&hout[((size_t)(tt * 8 + b)) * 512 + ji], hstore,
                               __ATOMIC_RELAXED, __HIP_MEMORY_SCOPE_AGENT);
        }
        if (rg == 0) { asm volatile("s_waitcnt vmcnt(0)" ::: "memory"); }
        if (tid == 0)
            __hip_atomic_store((layer ? f1 : f0) + (size_t)tt * 128 + blk, 1u,
                               __ATOMIC_RELAXED, __HIP_MEMORY_SCOPE_AGENT);
        if (layer && tid < 32) {
            int w = tid >> 3, b = tid & 7;
            h1b[((size_t)(tt * 8 + b)) * 512 + blk * 4 + w] = (u16)f2bf_rne(hstore);
        }
        // no end barrier: part[] rewrite at t+1 is ordered by the gates barrier above
    }
}

// ======================= banded attention (radius 50), bf16 out =======================
__global__ __launch_bounds__(128) void attn_kernel(const float* __restrict__ q,
                                                   const float* __restrict__ k,
                                                   const float* __restrict__ cnt,
                                                   const float* __restrict__ rel,
                                                   u16* __restrict__ outb)
{
    int t = blockIdx.x, h = blockIdx.y, b = blockIdx.z;
    int s_lo = max(0, t - R_), s_hi = min(L_ - 1, t + R_);
    int W = s_hi - s_lo + 1;
    int tid = threadIdx.x;

    __shared__ float qrow[64];
    __shared__ float dots[104];
    __shared__ float red[128];

    const float* qp = q + ((size_t)(b * L_ + t) * C_ + h * D_);
    if (tid < 64) qrow[tid] = qp[tid];
    __syncthreads();

    if (tid < W) {
        int s = s_lo + tid;
        const float* kp = k + ((size_t)(b * L_ + s) * C_ + h * D_);
        const float* rp = rel + (R_ + t - s) * D_;
        float acc = 0.f;
#pragma unroll 8
        for (int d = 0; d < 64; ++d)
            acc += qrow[d] * (kp[d] + 0.3f * rp[d]);
        dots[tid] = acc;
    }
    __syncthreads();

    red[tid] = (tid < W) ? dots[tid] : -INFINITY;
    __syncthreads();
    for (int s = 64; s > 0; s >>= 1) {
        if (tid < s) red[tid] = fmaxf(red[tid], red[tid + s]);
        __syncthreads();
    }
    float mx = red[0];
    __syncthreads();
    float e = 0.f;
    if (tid < W) { e = expf(dots[tid] - mx); dots[tid] = e; }
    red[tid] = e;
    __syncthreads();
    for (int s = 64; s > 0; s >>= 1) {
        if (tid < s) red[tid] += red[tid + s];
        __syncthreads();
    }
    float inv = 1.f / red[0];
    if (tid < W) dots[tid] *= inv;
    __syncthreads();

    if (tid < 64) {
        float acc = 0.f;
        const float* cb = cnt + ((size_t)(b * L_ + s_lo) * C_ + h * D_ + tid);
        const float* rb = rel + (R_ + t - s_lo) * D_ + tid;
        for (int i = 0; i < W; ++i)
            acc += dots[i] * (cb[(size_t)i * C_] + 0.3f * rb[-i * D_]);
        outb[(size_t)(b * L_ + t) * C_ + h * D_ + tid] = (u16)f2bf_rne(acc);
    }
}

// ======================= BatchNorm sums (coalesced, atomic) =======================
__global__ __launch_bounds__(512) void bn_sum(const float* __restrict__ fcout, float* __restrict__ stats)
{
    int c = threadIdx.x;
    float s = 0.f, ss = 0.f;
    for (int m = blockIdx.x; m < M_; m += 32) {
        float v = fcout[(size_t)m * 512 + c];
        s += v; ss += v * v;
    }
    atomicAdd(&stats[c], s);
    atomicAdd(&stats[512 + c], ss);
}

// ======================= BN apply + ReLU*scale + residual -> bf16 xfin =======================
__global__ __launch_bounds__(256) void bn_apply(const float* __restrict__ fcout,
                                                const float* __restrict__ stats,
                                                const float* __restrict__ bng, const float* __restrict__ bnb,
                                                const float* __restrict__ ascl,
                                                const float* __restrict__ h1tm,
                                                u16* __restrict__ xfinb)
{
    int idx = blockIdx.x * 256 + threadIdx.x;
    if (idx >= M_ * 512) return;
    int c = idx & 511;
    int m = idx >> 9;
    int b = m / L_, t = m - b * L_;
    float mean = stats[c] * (1.f / (float)M_);
    float var = stats[512 + c] * (1.f / (float)M_) - mean * mean;
    float rs = rsqrtf(fmaxf(var, 0.f) + 1e-5f);
    float v = (fcout[idx] - mean) * rs * bng[c] + bnb[c];
    v = fmaxf(v, 0.f) * ascl[c];
    xfinb[idx] = (u16)f2bf_rne(h1tm[((size_t)(t * 8 + b)) * 512 + c] + v);
}

// ======================= host launch =======================
extern "C" void kernel_launch(void* const* d_in, const int* in_sizes, int n_in,
                              void* d_out, int out_size, void* d_ws, size_t ws_size,
                              hipStream_t stream)
{
    const float* meg  = (const float*)d_in[0];
    const float* w1   = (const float*)d_in[1];
    const float* b1   = (const float*)d_in[2];
    const float* w2   = (const float*)d_in[3];
    const float* b2   = (const float*)d_in[4];
    const float* semb = (const float*)d_in[5];
    const float* Wih0 = (const float*)d_in[6];
    const float* Whh0 = (const float*)d_in[7];
    const float* bih0 = (const float*)d_in[8];
    const float* bhh0 = (const float*)d_in[9];
    const float* Wih1 = (const float*)d_in[10];
    const float* Whh1 = (const float*)d_in[11];
    const float* bih1 = (const float*)d_in[12];
    const float* bhh1 = (const float*)d_in[13];
    const float* qw   = (const float*)d_in[14];
    const float* qb   = (const float*)d_in[15];
    const float* kw   = (const float*)d_in[16];
    const float* kb   = (const float*)d_in[17];
    const float* cw   = (const float*)d_in[18];
    const float* cbi  = (const float*)d_in[19];
    const float* rel  = (const float*)d_in[20];
    const float* fcw  = (const float*)d_in[21];
    const float* fcb  = (const float*)d_in[22];
    const float* bng  = (const float*)d_in[23];
    const float* bnb  = (const float*)d_in[24];
    const float* ascl = (const float*)d_in[25];
    const float* outw = (const float*)d_in[26];
    const float* outb = (const float*)d_in[27];
    const int* subj = (const int*)d_in[28];
    float* out = (float*)d_out;

    float* ws = (float*)d_ws;
    // ---- arena (float-slot offsets), phase-overlaid ----
    // conv phase:
    u16*   x1b   = (u16*)(ws + 0);          // [8200][512] bf16
    u32*   w1p   = (u32*)(ws + 6562304);    // 512x546
    u32*   w2p   = (u32*)(ws + 6841856);    // 512x1024
    u16*   x2b   = (u16*)(ws + 4198400);    // [4104][576] bf16
    u32*   wih0p = (u32*)(ws + 14967296);   // 2048x288
    // LSTM phase:
    u32*   P0    = (u32*)(ws + 0);          // P0|P1|P2 contiguous (pack_w3)
    u32*   P1    = (u32*)(ws + 524288);
    u32*   P2    = (u32*)(ws + 1048576);
    u32*   flg   = (u32*)(ws + 1572864);    // f0[514][128] | f1[514][128] slots
    float* pre0  = ws + 6562304;            // [(t*8+b)][2048] fp32
    float* h0    = ws + 14967296;           // [t][b][c] fp32
    float* h1    = ws + 17068544;
    u16*   h1b   = (u16*)(ws + 19169792);   // bf16 mirror
    // post-LSTM phase:
    float* qb_f  = ws + 0;
    float* kb_f  = ws + 2101248;
    float* cb_f  = ws + 4202496;
    u16*   attno = (u16*)(ws + 6562304);    // bf16, over dead pre0
    float* fco   = ws + 8663552;
    float* stats = ws + 10764800;
    u32*   qwp   = (u32*)(ws + 10765824);   // contiguous: qwp|kwp|cwp|fcwp|outwp
    u32*   kwp   = (u32*)(ws + 10896896);
    u32*   cwp   = (u32*)(ws + 11027968);
    u32*   fcwp  = (u32*)(ws + 11159040);
    u32*   outwp = (u32*)(ws + 11290112);
    u16*   xfinb = (u16*)(ws + 19169792);   // bf16, overwrites dead h1b

    auto gemm = [&](const void* A, const u32* Bp, const float* bi1, const float* bi2,
                    float* Cf, u16* Cb, int Msz, int Nsz, int Ksz,
                    int lda, int ldc, int amode, int cmode, int relu) {
        dim3 g((Msz + 63) / 64, Nsz / 64);
        gemm_kernel<<<g, 256, 0, stream>>>(A, Bp, bi1, bi2, Cf, Cb,
                                           Msz, Nsz, Ksz, lda, ldc, amode, cmode, relu);
    };

    // ---- pack conv weights ----
    pack_b<<<(512 * 546 + 255) / 256, 256, 0, stream>>>(w1, w1p, 512, 1092);
    pack_w2k<<<2048, 256, 0, stream>>>(w2, w2p);

    // conv1 -> x1b bf16 [b*1025+t][512], relu
    gemm(meg, w1p, b1, nullptr, nullptr, x1b, M1_, 512, K1_, 0, 512, 2, 3, 1);
    // conv2 -> x2b bf16 [b*513+t][576] cols 0..511, relu
    gemm(x1b, w2p, b2, nullptr, nullptr, x2b, M_, 512, 2048, 0, CE_, 5, 3, 1);
    // subject embedding bf16 -> cols 512..575
    emb_kernel<<<(M_ * 64 + 255) / 256, 256, 0, stream>>>(semb, subj, x2b);

    // ---- pack LSTM (one launch) + pre0 weights ----
    pack_w3<<<6144, 256, 0, stream>>>(Whh0, Wih1, Whh1, P0);
    pack_b<<<(2048 * 288 + 255) / 256, 256, 0, stream>>>(Wih0, wih0p, 2048, 576);

    // layer-0 x-projection (bf16 A, packed B, time-major fp32 out, both biases)
    gemm(x2b, wih0p, bih0, bhh0, pre0, nullptr, M_, 2048, CE_, CE_, 2048, 6, 2, 0);

    // persistent fused 2-layer LSTM: ONE launch, fence-free flag-slot sync
    hipMemsetAsync(flg, 0, 2 * 514 * 128 * sizeof(u32), stream);
    lstm_persist<<<dim3(256), 256, 0, stream>>>(pre0, P0, P1, P2, bih1, bhh1,
                                                h0, h1, h1b, flg, flg + 514 * 128);

    // ---- pack post weights (one launch) + zero bn stats ----
    pack_post<<<(557056 + 255) / 256, 256, 0, stream>>>(qw, kw, cw, fcw, outw, qwp);
    hipMemsetAsync(stats, 0, 1024 * sizeof(float), stream);

    // fused q/k/cnt projections (bf16 h1b)
    gemm_qkv<<<dim3((M_ + 63) / 64, 24), 256, 0, stream>>>(h1b, qwp, kwp, cwp, qb, kb, cbi,
                                                           qb_f, kb_f, cb_f);

    attn_kernel<<<dim3(L_, H_, B_), 128, 0, stream>>>(qb_f, kb_f, cb_f, rel, attno);

    // fc (bf16 attno A) + BN(train) + relu*scale + residual -> xfinb bf16
    gemm(attno, fcwp, fcb, nullptr, fco, nullptr, M_, 512, 512, 512, 512, 6, 0, 0);
    bn_sum<<<32, 512, 0, stream>>>(fco, stats);
    bn_apply<<<(M_ * 512 + 255) / 256, 256, 0, stream>>>(fco, stats, bng, bnb, ascl, h1, xfinb);

    // final projection -> d_out [b][128][t] fp32 (bf16 xfin A)
    gemm(xfinb, outwp, outb, nullptr, out, nullptr, M_, 128, 512, 512, 0, 6, 1, 0);
}

// Round 6
// 3458.982 us; speedup vs baseline: 2.0372x; 1.4647x over previous
//
#include <hip/hip_runtime.h>
#include <cstdint>
#include <cmath>

typedef unsigned short u16;
typedef unsigned int u32;
typedef __attribute__((ext_vector_type(8))) short bf16x8;
typedef __attribute__((ext_vector_type(4))) float f32x4;
typedef __attribute__((ext_vector_type(4))) unsigned int u32x4;

// ---- model dims ----
#define B_    8
#define T_IN  2048
#define CIN1  273
#define L1_   1025
#define L_    513
#define C_    512
#define CE_   576
#define M1_   (B_*L1_)   /* 8200 */
#define M_    (B_*L_)    /* 4104 */
#define K1_   (CIN1*4)   /* 1092 */
#define H_    8
#define D_    64
#define R_    50

__device__ __forceinline__ u32 f2bf_rne(float f) {
    u32 x = __float_as_uint(f);
    return (x + 0x7fffu + ((x >> 16) & 1u)) >> 16;
}

// ======================= A-pair loader: returns packed bf16x2 for (k, k+1), k even ==============
// amode: 2 conv1 im2col from meg (fp32); 5 conv2 im2col from x1b (bf16, k-order kk*512+ci);
//        6 bf16 rowmajor(lda)
__device__ __forceinline__ u32 a_pair(const void* A, int m, int k, int lda, int amode, int Ksz) {
    if (amode == 2) {
        if (k >= K1_) return 0;
        int b = m / L1_, t = m - b * L1_;
        int ci = k >> 2, kk = k & 3;
        int it = 2 * t - 2 + kk;
        const float* mg = (const float*)A + ((size_t)(b * CIN1 + ci)) * T_IN;
        u32 lo = ((unsigned)it < (unsigned)T_IN)       ? f2bf_rne(mg[it])     : 0;
        u32 hi = ((unsigned)(it + 1) < (unsigned)T_IN) ? f2bf_rne(mg[it + 1]) : 0;
        return lo | (hi << 16);
    } else if (amode == 5) {
        int b = m / L_, t = m - b * L_;
        int kk = k >> 9, ci = k & 511;
        int it = 2 * t - 2 + kk;
        if ((unsigned)it >= (unsigned)L1_) return 0;
        return *(const u32*)((const u16*)A + ((size_t)(b * L1_ + it)) * 512 + ci);
    } else {
        return *(const u32*)((const u16*)A + (size_t)m * lda + k);
    }
}

// ======================= MFMA GEMM 64x64 (packed bf16 B) =======================
// cmode: 0 fp32 C[m*ldc+n]; 1 out[b][n][t] (n<128); 2 fp32 [(t*8+b)*ldc+n]; 3 bf16 Cb[m*ldc+n]
__global__ __launch_bounds__(256) void gemm_kernel(
    const void* __restrict__ Aptr, const u32* __restrict__ Bp,
    const float* __restrict__ bias1, const float* __restrict__ bias2,
    float* __restrict__ Cf, u16* __restrict__ Cb,
    int Msz, int Nsz, int Ksz, int lda, int ldc, int amode, int cmode, int relu)
{
    __shared__ u16 As[64][40];
    __shared__ u16 Bs[64][40];

    int tid = threadIdx.x;
    int m0 = blockIdx.x * 64, n0 = blockIdx.y * 64;
    int wv = tid >> 6, lane = tid & 63;
    int lm = lane & 15, quad = lane >> 4;
    int kp = tid & 15, rw = tid >> 4;
    int Kh = Ksz >> 1;

    f32x4 acc[4];
#pragma unroll
    for (int nt = 0; nt < 4; ++nt)
#pragma unroll
        for (int r = 0; r < 4; ++r) acc[nt][r] = 0.f;

    for (int k0 = 0; k0 < Ksz; k0 += 32) {
        int pidx = (k0 >> 1) + kp;
#pragma unroll
        for (int i = 0; i < 4; ++i) {
            int row = rw + 16 * i;
            int k = k0 + 2 * kp;
            int m = m0 + row;
            u32 aw = 0;
            if (m < Msz && k < Ksz) aw = a_pair(Aptr, m, k, lda, amode, Ksz);
            *(u32*)&As[row][2 * kp] = aw;
            u32 bw = 0;
            if (pidx < Kh) bw = Bp[(size_t)(n0 + row) * Kh + pidx];
            *(u32*)&Bs[row][2 * kp] = bw;
        }
        __syncthreads();

        bf16x8 af = *(const bf16x8*)&As[wv * 16 + lm][quad * 8];
#pragma unroll
        for (int nt = 0; nt < 4; ++nt) {
            bf16x8 bf = *(const bf16x8*)&Bs[nt * 16 + lm][quad * 8];
            acc[nt] = __builtin_amdgcn_mfma_f32_16x16x32_bf16(af, bf, acc[nt], 0, 0, 0);
        }
        __syncthreads();
    }

#pragma unroll
    for (int nt = 0; nt < 4; ++nt) {
#pragma unroll
        for (int r = 0; r < 4; ++r) {
            int m = m0 + wv * 16 + quad * 4 + r;
            if (m >= Msz) continue;
            int n = n0 + nt * 16 + lm;
            float v = acc[nt][r] + bias1[n] + (bias2 ? bias2[n] : 0.f);
            if (relu) v = fmaxf(v, 0.f);
            if (cmode == 0) {
                Cf[(size_t)m * ldc + n] = v;
            } else if (cmode == 1) {
                int b = m / L_, t = m - b * L_;
                Cf[((size_t)(b * 128 + n)) * L_ + t] = v;
            } else if (cmode == 2) {
                int b = m / L_, t = m - b * L_;
                Cf[((size_t)(t * 8 + b)) * ldc + n] = v;
            } else {
                Cb[(size_t)m * ldc + n] = (u16)f2bf_rne(v);
            }
        }
    }
}

// ======================= fused q/k/cnt projection GEMM (bf16 h1b A, packed B) ==================
__global__ __launch_bounds__(256) void gemm_qkv(
    const u16* __restrict__ h1b,
    const u32* __restrict__ qwp, const u32* __restrict__ kwp, const u32* __restrict__ cwp,
    const float* __restrict__ qb, const float* __restrict__ kb, const float* __restrict__ cb,
    float* __restrict__ qo, float* __restrict__ ko, float* __restrict__ co)
{
    __shared__ u16 As[64][40];
    __shared__ u16 Bs[64][40];

    int tid = threadIdx.x;
    int which = blockIdx.y >> 3;
    int m0 = blockIdx.x * 64, n0 = (blockIdx.y & 7) * 64;
    const u32* Bp = which == 0 ? qwp : (which == 1 ? kwp : cwp);
    const float* bias = which == 0 ? qb : (which == 1 ? kb : cb);
    float* Cf = which == 0 ? qo : (which == 1 ? ko : co);

    int wv = tid >> 6, lane = tid & 63;
    int lm = lane & 15, quad = lane >> 4;
    int kp = tid & 15, rw = tid >> 4;

    f32x4 acc[4];
#pragma unroll
    for (int nt = 0; nt < 4; ++nt)
#pragma unroll
        for (int r = 0; r < 4; ++r) acc[nt][r] = 0.f;

    for (int k0 = 0; k0 < 512; k0 += 32) {
#pragma unroll
        for (int i = 0; i < 4; ++i) {
            int row = rw + 16 * i;
            int k = k0 + 2 * kp;
            int m = m0 + row;
            u32 aw = 0;
            if (m < M_) {
                int b = m / L_, t = m - b * L_;
                aw = *(const u32*)(h1b + ((size_t)(t * 8 + b)) * 512 + k);
            }
            *(u32*)&As[row][2 * kp] = aw;
            *(u32*)&Bs[row][2 * kp] = Bp[(size_t)(n0 + row) * 256 + (k0 >> 1) + kp];
        }
        __syncthreads();

        bf16x8 af = *(const bf16x8*)&As[wv * 16 + lm][quad * 8];
#pragma unroll
        for (int nt = 0; nt < 4; ++nt) {
            bf16x8 bf = *(const bf16x8*)&Bs[nt * 16 + lm][quad * 8];
            acc[nt] = __builtin_amdgcn_mfma_f32_16x16x32_bf16(af, bf, acc[nt], 0, 0, 0);
        }
        __syncthreads();
    }

#pragma unroll
    for (int nt = 0; nt < 4; ++nt) {
#pragma unroll
        for (int r = 0; r < 4; ++r) {
            int m = m0 + wv * 16 + quad * 4 + r;
            if (m >= M_) continue;
            int n = n0 + nt * 16 + lm;
            Cf[(size_t)m * 512 + n] = acc[nt][r] + bias[n];
        }
    }
}

// ======================= subject embedding concat (bf16) =======================
__global__ __launch_bounds__(256) void emb_kernel(const float* __restrict__ semb,
                                                  const int* __restrict__ subj,
                                                  u16* __restrict__ x2b)
{
    int idx = blockIdx.x * 256 + threadIdx.x;
    if (idx >= M_ * 64) return;
    int m = idx >> 6, e = idx & 63;
    int b = m / L_;
    x2b[(size_t)m * CE_ + 512 + e] = (u16)f2bf_rne(semb[subj[b] * 64 + e]);
}

// ======================= generic weight pack: fp32 [N][K] -> bf16 pairs [N][K/2] ================
__global__ __launch_bounds__(256) void pack_b(const float* __restrict__ W, u32* __restrict__ P,
                                              int N, int K)
{
    int gid = blockIdx.x * 256 + threadIdx.x;
    int Kh = K >> 1;
    if (gid >= N * Kh) return;
    int n = gid / Kh, p = gid - n * Kh;
    int k = 2 * p;
    u32 lo = f2bf_rne(W[(size_t)n * K + k]);
    u32 hi = f2bf_rne(W[(size_t)n * K + k + 1]);
    P[gid] = lo | (hi << 16);
}

// ======================= fused post-weight pack: qw/kw/cw/fcw (512x512) + outw (128x512) ========
__global__ __launch_bounds__(256) void pack_post(const float* __restrict__ qw,
                                                 const float* __restrict__ kw,
                                                 const float* __restrict__ cw,
                                                 const float* __restrict__ fcw,
                                                 const float* __restrict__ outw,
                                                 u32* __restrict__ P)
{
    int gid = blockIdx.x * 256 + threadIdx.x;   // 557056 total
    if (gid >= 557056) return;
    const float* W;
    int local;
    if (gid < 524288) {
        int wsel = gid >> 17;
        W = wsel == 0 ? qw : (wsel == 1 ? kw : (wsel == 2 ? cw : fcw));
        local = gid & 131071;
    } else {
        W = outw;
        local = gid - 524288;
    }
    int n = local >> 8, p = local & 255;
    int k = 2 * p;
    u32 lo = f2bf_rne(W[(size_t)n * 512 + k]);
    u32 hi = f2bf_rne(W[(size_t)n * 512 + k + 1]);
    P[gid] = lo | (hi << 16);
}

// ======================= w2 pack with k-reorder: k' = kk*512 + ci =======================
__global__ __launch_bounds__(256) void pack_w2k(const float* __restrict__ W, u32* __restrict__ P)
{
    int gid = blockIdx.x * 256 + threadIdx.x;   // 512*1024
    int n = gid >> 10, p = gid & 1023;
    int kk = p >> 8, ci = (2 * p) & 511;
    u32 lo = f2bf_rne(W[(size_t)n * 2048 + ci * 4 + kk]);
    u32 hi = f2bf_rne(W[(size_t)n * 2048 + ci * 4 + 4 + kk]);
    P[gid] = lo | (hi << 16);
}

// ======================= fused LSTM weight pack: Whh0/Wih1/Whh1 in one launch ===================
__global__ __launch_bounds__(256) void pack_w3(const float* __restrict__ W0,
                                               const float* __restrict__ W1,
                                               const float* __restrict__ W2,
                                               u32* __restrict__ P)   // P0|P1|P2 contiguous
{
    int gid3 = blockIdx.x * 256 + threadIdx.x;  // 3*524288
    int src = gid3 >> 19;
    int gid = gid3 & 524287;
    const float* W = src == 0 ? W0 : (src == 1 ? W1 : W2);
    int r = gid & 1, lane = (gid >> 1) & 63, i2 = (gid >> 7) & 1;
    int g = (gid >> 8) & 3, j = gid >> 10;
    int row = g * 512 + j;
    int c0 = 4 * (lane + 64 * i2) + 2 * r;
    u32 lo = f2bf_rne(W[(size_t)row * 512 + c0]);
    u32 hi = f2bf_rne(W[(size_t)row * 512 + c0 + 1]);
    P[gid3] = lo | (hi << 16);
}

// ======================= sentinel-sync helpers =======================
// Sentinel = 0xFFFFFFFF (a NaN). h = sigmoid*tanh is always finite -> pattern unreachable.
// All 4 words are checked, so only per-DWORD store atomicity is assumed (guaranteed).
// Monotone protocol: a slot only ever transitions sentinel -> final value, so any stale
// read returns sentinel and self-heals via retry. No flags, no fences, no cache flushes.
// NOTE: all asm operands use ext_vector types (f32x4) -- HIP float4 structs are not valid
// inline-asm "v" inputs (r5 compile failure).
__device__ __forceinline__ bool sent4(f32x4 v) {
    u32x4 u;
    __builtin_memcpy(&u, &v, 16);
    return (u.x == 0xFFFFFFFFu) | (u.y == 0xFFFFFFFFu) |
           (u.z == 0xFFFFFFFFu) | (u.w == 0xFFFFFFFFu);
}
__device__ __forceinline__ f32x4 ld1v(const f32x4* p) {
    f32x4 r;
    asm volatile("global_load_dwordx4 %0, %1, off sc0 sc1\n\ts_waitcnt vmcnt(0)"
                 : "=v"(r) : "v"(p) : "memory");
    return r;
}
// Stage one 16KB h slab (8 b x 128 j-quads) cooperatively: wave rg loads b in {2rg, 2rg+1},
// validates sentinels (retry), writes to LDS. sc0 sc1 loads bypass L1/L2 -> read L3 directly.
__device__ __forceinline__ void stage_h(const float* slab, f32x4* dst, int l, int rg) {
    const f32x4* s4 = (const f32x4*)slab;
    const f32x4* pa = s4 + (2 * rg) * 128 + l;
    const f32x4* pb = s4 + (2 * rg + 1) * 128 + l;
    f32x4 h0, h1, h2, h3;
    asm volatile(
        "global_load_dwordx4 %0, %4, off sc0 sc1\n\t"
        "global_load_dwordx4 %1, %4, off offset:1024 sc0 sc1\n\t"
        "global_load_dwordx4 %2, %5, off sc0 sc1\n\t"
        "global_load_dwordx4 %3, %5, off offset:1024 sc0 sc1\n\t"
        "s_waitcnt vmcnt(0)"
        : "=&v"(h0), "=&v"(h1), "=&v"(h2), "=&v"(h3)
        : "v"(pa), "v"(pb)
        : "memory");
    while (sent4(h0)) h0 = ld1v(pa);
    while (sent4(h1)) h1 = ld1v(pa + 64);
    while (sent4(h2)) h2 = ld1v(pb);
    while (sent4(h3)) h3 = ld1v(pb + 64);
    dst[(2 * rg) * 128 + l] = h0;
    dst[(2 * rg) * 128 + 64 + l] = h1;
    dst[(2 * rg + 1) * 128 + l] = h2;
    dst[(2 * rg + 1) * 128 + 64 + l] = h3;
}
__device__ __forceinline__ void stage_zero(f32x4* dst, int l, int rg) {
    const f32x4 z4 = 0.f;
    dst[(2 * rg) * 128 + l] = z4;
    dst[(2 * rg) * 128 + 64 + l] = z4;
    dst[(2 * rg + 1) * 128 + l] = z4;
    dst[(2 * rg + 1) * 128 + 64 + l] = z4;
}

// ======================= persistent fused 2-layer LSTM (sentinel-in-data sync) =================
// One launch, all 513 steps. 256 blocks (0-127: layer 0, 128-255: layer 1, skewed one step).
// r2's proven skeleton (LDS staging, wave-per-j FMA, part/gates reduce) with the flag protocol
// replaced by sentinel-polled data loads, and L1's ih-GEMV (input ready early) hoisted BEFORE
// the critical h1[tt-1] wait. Producer publishes each (b, j-quad) h slice as ONE 16B
// global_store_dwordx4 sc0 sc1 -- the store IS the publish.
__global__ __launch_bounds__(256, 1) void lstm_persist(
    const float* __restrict__ pre0,
    const u32* __restrict__ P0,
    const u32* __restrict__ P1,
    const u32* __restrict__ P2,
    const float* __restrict__ bih1,
    const float* __restrict__ bhh1,
    float* __restrict__ h0seq,
    float* __restrict__ h1seq,
    u16* __restrict__ h1b)
{
    const int layer = blockIdx.x >> 7;
    const int blk = blockIdx.x & 127;
    const int tid = threadIdx.x;
    const int l = tid & 63;
    const int rg = tid >> 6;
    const int j = blk * 4 + rg;

    __shared__ f32x4 hA4[1024];
    __shared__ f32x4 hB4[1024];
    __shared__ float part[4 * 8 * 33];
    __shared__ float gates[4 * 33];

    // ---- weights once into registers (pack_w3 layout, r2-proven) ----
    const u32* wA = (layer ? P2 : P0) + (size_t)j * 1024;
    uint2 wra[8], wrb[8];
#pragma unroll
    for (int i2 = 0; i2 < 2; ++i2)
#pragma unroll
        for (int g = 0; g < 4; ++g)
            wra[i2 * 4 + g] = *(const uint2*)&wA[(g * 2 + i2) * 128 + l * 2];
    if (layer) {
        const u32* wB = P1 + (size_t)j * 1024;
#pragma unroll
        for (int i2 = 0; i2 < 2; ++i2)
#pragma unroll
            for (int g = 0; g < 4; ++g)
                wrb[i2 * 4 + g] = *(const uint2*)&wB[(g * 2 + i2) * 128 + l * 2];
    }

    // per-thread constants for the gate assembly phase
    int fb = 0, grow = 0;
    float bias1 = 0.f;
    if (tid < 128) {
        int fw = tid >> 5;
        fb = tid & 7;
        grow = ((tid & 31) >> 3) * 512 + blk * 4 + fw;
        if (layer) bias1 = bih1[grow] + bhh1[grow];   // layer-1 pre is step-invariant
    }

    float creg = 0.f;   // c-state (tid<32), registers across steps

    for (int t = 0; t <= L_; ++t) {
        bool active = layer ? (t >= 1) : (t < L_);
        if (!active) continue;
        int tt = layer ? (t - 1) : t;

        // hoist pre0 load (plain; latency overlaps staging)
        float mypre = 0.f;
        if (tid < 128)
            mypre = layer ? bias1 : pre0[((size_t)(tt * 8 + fb)) * 2048 + grow];

        float acc[4][8];
#pragma unroll
        for (int g = 0; g < 4; ++g)
#pragma unroll
            for (int b = 0; b < 8; ++b) acc[g][b] = 0.f;

        // ---- L1 phase A: ih-GEMV over h0[tt] (ready early; off the h1 critical path) ----
        if (layer) {
            stage_h(h0seq + (size_t)tt * 4096, hB4, l, rg);
            __syncthreads();
#pragma unroll
            for (int i2 = 0; i2 < 2; ++i2) {
                int cq = l + 64 * i2;
                f32x4 hv[8];
#pragma unroll
                for (int b = 0; b < 8; ++b) hv[b] = hB4[b * 128 + cq];
#pragma unroll
                for (int g = 0; g < 4; ++g) {
                    uint2 ww = wrb[i2 * 4 + g];
                    float w0 = __uint_as_float(ww.x << 16);
                    float w1 = __uint_as_float(ww.x & 0xffff0000u);
                    float w2 = __uint_as_float(ww.y << 16);
                    float w3 = __uint_as_float(ww.y & 0xffff0000u);
#pragma unroll
                    for (int b = 0; b < 8; ++b)
                        acc[g][b] = fmaf(w0, hv[b].x, fmaf(w1, hv[b].y,
                                    fmaf(w2, hv[b].z, fmaf(w3, hv[b].w, acc[g][b]))));
                }
            }
        }

        // ---- hh-GEMV over own h[tt-1] (the recurrence-critical input) ----
        if (tt > 0)
            stage_h((layer ? h1seq : h0seq) + (size_t)(tt - 1) * 4096, hA4, l, rg);
        else
            stage_zero(hA4, l, rg);
        __syncthreads();

#pragma unroll
        for (int i2 = 0; i2 < 2; ++i2) {
            int cq = l + 64 * i2;
            f32x4 hv[8];
#pragma unroll
            for (int b = 0; b < 8; ++b) hv[b] = hA4[b * 128 + cq];
#pragma unroll
            for (int g = 0; g < 4; ++g) {
                uint2 ww = wra[i2 * 4 + g];
                float w0 = __uint_as_float(ww.x << 16);
                float w1 = __uint_as_float(ww.x & 0xffff0000u);
                float w2 = __uint_as_float(ww.y << 16);
                float w3 = __uint_as_float(ww.y & 0xffff0000u);
#pragma unroll
                for (int b = 0; b < 8; ++b)
                    acc[g][b] = fmaf(w0, hv[b].x, fmaf(w1, hv[b].y,
                                fmaf(w2, hv[b].z, fmaf(w3, hv[b].w, acc[g][b]))));
            }
        }

        // ---- intra-wave column reduce (r2-proven) ----
#pragma unroll
        for (int m = 8; m <= 32; m <<= 1)
#pragma unroll
            for (int g = 0; g < 4; ++g)
#pragma unroll
                for (int b = 0; b < 8; ++b)
                    acc[g][b] += __shfl_xor(acc[g][b], m);
        if (l < 8) {
#pragma unroll
            for (int g = 0; g < 4; ++g)
#pragma unroll
                for (int b = 0; b < 8; ++b)
                    part[(rg * 8 + l) * 33 + g * 8 + b] = acc[g][b];
        }
        __syncthreads();

        if (tid < 128) {
            int w = tid >> 5, x = tid & 31;
            float s = 0.f;
#pragma unroll
            for (int p = 0; p < 8; ++p) s += part[(w * 8 + p) * 33 + x];
            gates[w * 33 + x] = s + mypre;
        }
        __syncthreads();

        // ---- nonlinearity + 16B sentinel-clearing publish ----
        if (tid < 32) {
            int w = tid >> 3, b = tid & 7;
            float gi = gates[w * 33 + 0 * 8 + b];
            float gf = gates[w * 33 + 1 * 8 + b];
            float gg = gates[w * 33 + 2 * 8 + b];
            float go = gates[w * 33 + 3 * 8 + b];
            float cprev = (tt == 0) ? 0.f : creg;
            float si = 1.f / (1.f + expf(-gi));
            float sf = 1.f / (1.f + expf(-gf));
            float so = 1.f / (1.f + expf(-go));
            float cn = sf * cprev + si * tanhf(gg);
            creg = cn;
            float hstore = so * tanhf(cn);
            // gather the 4 j-values of each batch into lane b (w=0..3 live in lanes b+8w)
            float y1 = __shfl_xor(hstore, 8);
            float y2 = __shfl_xor(hstore, 16);
            float y3 = __shfl_xor(hstore, 24);
            if (tid < 8) {
                f32x4 hs;
                hs.x = hstore; hs.y = y1; hs.z = y2; hs.w = y3;
                f32x4* hp = (f32x4*)(layer ? h1seq : h0seq)
                            + ((size_t)(tt * 8 + tid)) * 128 + blk;
                asm volatile("global_store_dwordx4 %0, %1, off sc0 sc1"
                             :: "v"(hp), "v"(hs) : "memory");
                if (layer) {
                    u32 lo = f2bf_rne(hs.x) | (f2bf_rne(hs.y) << 16);
                    u32 hi = f2bf_rne(hs.z) | (f2bf_rne(hs.w) << 16);
                    *(uint2*)&h1b[((size_t)(tt * 8 + tid)) * 512 + blk * 4] = make_uint2(lo, hi);
                }
            }
        }
        // no trailing barrier: next-step LDS rewrites are ordered by the two reduce barriers
    }
}

// ======================= banded attention (radius 50), bf16 out =======================
__global__ __launch_bounds__(128) void attn_kernel(const float* __restrict__ q,
                                                   const float* __restrict__ k,
                                                   const float* __restrict__ cnt,
                                                   const float* __restrict__ rel,
                                                   u16* __restrict__ outb)
{
    int t = blockIdx.x, h = blockIdx.y, b = blockIdx.z;
    int s_lo = max(0, t - R_), s_hi = min(L_ - 1, t + R_);
    int W = s_hi - s_lo + 1;
    int tid = threadIdx.x;

    __shared__ float qrow[64];
    __shared__ float dots[104];
    __shared__ float red[128];

    const float* qp = q + ((size_t)(b * L_ + t) * C_ + h * D_);
    if (tid < 64) qrow[tid] = qp[tid];
    __syncthreads();

    if (tid < W) {
        int s = s_lo + tid;
        const float* kp = k + ((size_t)(b * L_ + s) * C_ + h * D_);
        const float* rp = rel + (R_ + t - s) * D_;
        float acc = 0.f;
#pragma unroll 8
        for (int d = 0; d < 64; ++d)
            acc += qrow[d] * (kp[d] + 0.3f * rp[d]);
        dots[tid] = acc;
    }
    __syncthreads();

    red[tid] = (tid < W) ? dots[tid] : -INFINITY;
    __syncthreads();
    for (int s = 64; s > 0; s >>= 1) {
        if (tid < s) red[tid] = fmaxf(red[tid], red[tid + s]);
        __syncthreads();
    }
    float mx = red[0];
    __syncthreads();
    float e = 0.f;
    if (tid < W) { e = expf(dots[tid] - mx); dots[tid] = e; }
    red[tid] = e;
    __syncthreads();
    for (int s = 64; s > 0; s >>= 1) {
        if (tid < s) red[tid] += red[tid + s];
        __syncthreads();
    }
    float inv = 1.f / red[0];
    if (tid < W) dots[tid] *= inv;
    __syncthreads();

    if (tid < 64) {
        float acc = 0.f;
        const float* cb = cnt + ((size_t)(b * L_ + s_lo) * C_ + h * D_ + tid);
        const float* rb = rel + (R_ + t - s_lo) * D_ + tid;
        for (int i = 0; i < W; ++i)
            acc += dots[i] * (cb[(size_t)i * C_] + 0.3f * rb[-i * D_]);
        outb[(size_t)(b * L_ + t) * C_ + h * D_ + tid] = (u16)f2bf_rne(acc);
    }
}

// ======================= BatchNorm sums (coalesced, atomic) =======================
__global__ __launch_bounds__(512) void bn_sum(const float* __restrict__ fcout, float* __restrict__ stats)
{
    int c = threadIdx.x;
    float s = 0.f, ss = 0.f;
    for (int m = blockIdx.x; m < M_; m += 32) {
        float v = fcout[(size_t)m * 512 + c];
        s += v; ss += v * v;
    }
    atomicAdd(&stats[c], s);
    atomicAdd(&stats[512 + c], ss);
}

// ======================= BN apply + ReLU*scale + residual -> bf16 xfin =======================
__global__ __launch_bounds__(256) void bn_apply(const float* __restrict__ fcout,
                                                const float* __restrict__ stats,
                                                const float* __restrict__ bng, const float* __restrict__ bnb,
                                                const float* __restrict__ ascl,
                                                const float* __restrict__ h1tm,
                                                u16* __restrict__ xfinb)
{
    int idx = blockIdx.x * 256 + threadIdx.x;
    if (idx >= M_ * 512) return;
    int c = idx & 511;
    int m = idx >> 9;
    int b = m / L_, t = m - b * L_;
    float mean = stats[c] * (1.f / (float)M_);
    float var = stats[512 + c] * (1.f / (float)M_) - mean * mean;
    float rs = rsqrtf(fmaxf(var, 0.f) + 1e-5f);
    float v = (fcout[idx] - mean) * rs * bng[c] + bnb[c];
    v = fmaxf(v, 0.f) * ascl[c];
    xfinb[idx] = (u16)f2bf_rne(h1tm[((size_t)(t * 8 + b)) * 512 + c] + v);
}

// ======================= host launch =======================
extern "C" void kernel_launch(void* const* d_in, const int* in_sizes, int n_in,
                              void* d_out, int out_size, void* d_ws, size_t ws_size,
                              hipStream_t stream)
{
    const float* meg  = (const float*)d_in[0];
    const float* w1   = (const float*)d_in[1];
    const float* b1   = (const float*)d_in[2];
    const float* w2   = (const float*)d_in[3];
    const float* b2   = (const float*)d_in[4];
    const float* semb = (const float*)d_in[5];
    const float* Wih0 = (const float*)d_in[6];
    const float* Whh0 = (const float*)d_in[7];
    const float* bih0 = (const float*)d_in[8];
    const float* bhh0 = (const float*)d_in[9];
    const float* Wih1 = (const float*)d_in[10];
    const float* Whh1 = (const float*)d_in[11];
    const float* bih1 = (const float*)d_in[12];
    const float* bhh1 = (const float*)d_in[13];
    const float* qw   = (const float*)d_in[14];
    const float* qb   = (const float*)d_in[15];
    const float* kw   = (const float*)d_in[16];
    const float* kb   = (const float*)d_in[17];
    const float* cw   = (const float*)d_in[18];
    const float* cbi  = (const float*)d_in[19];
    const float* rel  = (const float*)d_in[20];
    const float* fcw  = (const float*)d_in[21];
    const float* fcb  = (const float*)d_in[22];
    const float* bng  = (const float*)d_in[23];
    const float* bnb  = (const float*)d_in[24];
    const float* ascl = (const float*)d_in[25];
    const float* outw = (const float*)d_in[26];
    const float* outb = (const float*)d_in[27];
    const int* subj = (const int*)d_in[28];
    float* out = (float*)d_out;

    float* ws = (float*)d_ws;
    // ---- arena (float-slot offsets), phase-overlaid ----
    // conv phase:
    u16*   x1b   = (u16*)(ws + 0);          // [8200][512] bf16
    u32*   w1p   = (u32*)(ws + 6562304);    // 512x546
    u32*   w2p   = (u32*)(ws + 6841856);    // 512x1024
    u16*   x2b   = (u16*)(ws + 4198400);    // [4104][576] bf16
    u32*   wih0p = (u32*)(ws + 14967296);   // 2048x288
    // LSTM phase:
    u32*   P0    = (u32*)(ws + 0);          // P0|P1|P2 contiguous (pack_w3)
    u32*   P1    = (u32*)(ws + 524288);
    u32*   P2    = (u32*)(ws + 1048576);
    float* pre0  = ws + 6562304;            // [(t*8+b)][2048] fp32
    float* h0    = ws + 14967296;           // [t][b][c] fp32 (sentinel-init)
    float* h1    = ws + 17068544;
    u16*   h1b   = (u16*)(ws + 19169792);   // bf16 mirror
    // post-LSTM phase:
    float* qb_f  = ws + 0;
    float* kb_f  = ws + 2101248;
    float* cb_f  = ws + 4202496;
    u16*   attno = (u16*)(ws + 6562304);    // bf16, over dead pre0
    float* fco   = ws + 8663552;
    float* stats = ws + 10764800;
    u32*   qwp   = (u32*)(ws + 10765824);   // contiguous: qwp|kwp|cwp|fcwp|outwp
    u32*   kwp   = (u32*)(ws + 10896896);
    u32*   cwp   = (u32*)(ws + 11027968);
    u32*   fcwp  = (u32*)(ws + 11159040);
    u32*   outwp = (u32*)(ws + 11290112);
    u16*   xfinb = (u16*)(ws + 19169792);   // bf16, overwrites dead h1b

    auto gemm = [&](const void* A, const u32* Bp, const float* bi1, const float* bi2,
                    float* Cf, u16* Cb, int Msz, int Nsz, int Ksz,
                    int lda, int ldc, int amode, int cmode, int relu) {
        dim3 g((Msz + 63) / 64, Nsz / 64);
        gemm_kernel<<<g, 256, 0, stream>>>(A, Bp, bi1, bi2, Cf, Cb,
                                           Msz, Nsz, Ksz, lda, ldc, amode, cmode, relu);
    };

    // ---- pack conv weights ----
    pack_b<<<(512 * 546 + 255) / 256, 256, 0, stream>>>(w1, w1p, 512, 1092);
    pack_w2k<<<2048, 256, 0, stream>>>(w2, w2p);

    // conv1 -> x1b bf16 [b*1025+t][512], relu
    gemm(meg, w1p, b1, nullptr, nullptr, x1b, M1_, 512, K1_, 0, 512, 2, 3, 1);
    // conv2 -> x2b bf16 [b*513+t][576] cols 0..511, relu
    gemm(x1b, w2p, b2, nullptr, nullptr, x2b, M_, 512, 2048, 0, CE_, 5, 3, 1);
    // subject embedding bf16 -> cols 512..575
    emb_kernel<<<(M_ * 64 + 255) / 256, 256, 0, stream>>>(semb, subj, x2b);

    // ---- pack LSTM (one launch) + pre0 weights ----
    pack_w3<<<6144, 256, 0, stream>>>(Whh0, Wih1, Whh1, P0);
    pack_b<<<(2048 * 288 + 255) / 256, 256, 0, stream>>>(Wih0, wih0p, 2048, 576);

    // layer-0 x-projection (bf16 A, packed B, time-major fp32 out, both biases)
    gemm(x2b, wih0p, bih0, bhh0, pre0, nullptr, M_, 2048, CE_, CE_, 2048, 6, 2, 0);

    // sentinel-init h arrays (0xFF bytes = NaN pattern), then ONE persistent LSTM launch
    (void)hipMemsetAsync(h0, 0xFF, 2101248 * sizeof(float), stream);
    (void)hipMemsetAsync(h1, 0xFF, 2101248 * sizeof(float), stream);
    lstm_persist<<<dim3(256), 256, 0, stream>>>(pre0, P0, P1, P2, bih1, bhh1, h0, h1, h1b);

    // ---- pack post weights (one launch) + zero bn stats ----
    pack_post<<<(557056 + 255) / 256, 256, 0, stream>>>(qw, kw, cw, fcw, outw, qwp);
    (void)hipMemsetAsync(stats, 0, 1024 * sizeof(float), stream);

    // fused q/k/cnt projections (bf16 h1b)
    gemm_qkv<<<dim3((M_ + 63) / 64, 24), 256, 0, stream>>>(h1b, qwp, kwp, cwp, qb, kb, cbi,
                                                           qb_f, kb_f, cb_f);

    attn_kernel<<<dim3(L_, H_, B_), 128, 0, stream>>>(qb_f, kb_f, cb_f, rel, attno);

    // fc (bf16 attno A) + BN(train) + relu*scale + residual -> xfinb bf16
    gemm(attno, fcwp, fcb, nullptr, fco, nullptr, M_, 512, 512, 512, 512, 6, 0, 0);
    bn_sum<<<32, 512, 0, stream>>>(fco, stats);
    bn_apply<<<(M_ * 512 + 255) / 256, 256, 0, stream>>>(fco, stats, bng, bnb, ascl, h1, xfinb);

    // final projection -> d_out [b][128][t] fp32 (bf16 xfin A)
    gemm(xfinb, outwp, outb, nullptr, out, nullptr, M_, 128, 512, 512, 0, 6, 1, 0);
}